// Round 2
// baseline (69.362 us; speedup 1.0000x reference)
//
#include <hip/hip_runtime.h>

// NCT system simulator: RK4 rollout of a 2-D affine system, 512 steps,
// B=65536 independent elements. Per-step map is affine with constant
// per-element coefficients -> precompute A (2x2) and d (2) once per thread,
// then the step loop is 2 FMA-chains (state) + 3 accumulator chains (reward).

#define DT_F 0.01f
#define P1_F 1.0f
#define P2_F 0.1f
#define PA_F 0.01f
#define TERM_SCALE_F 10.0f

// One RK4 step of ds/dt = (x2, x1 + c) with c constant over the step.
// Linear in (x1, x2, c); used to build the per-element affine map by
// evaluating on homogeneous basis vectors.
__device__ __forceinline__ void rk4_step(float x1, float x2, float c,
                                         float& nx, float& ny) {
    const float h  = DT_F;
    const float hh = 0.5f * DT_F;
    const float h6 = DT_F / 6.0f;
    float k1x = x2;
    float k1y = x1 + c;
    float a2x = fmaf(hh, k1x, x1);
    float a2y = fmaf(hh, k1y, x2);
    float k2x = a2y;
    float k2y = a2x + c;
    float a3x = fmaf(hh, k2x, x1);
    float a3y = fmaf(hh, k2y, x2);
    float k3x = a3y;
    float k3y = a3x + c;
    float a4x = fmaf(h, k3x, x1);
    float a4y = fmaf(h, k3y, x2);
    float k4x = a4y;
    float k4y = a4x + c;
    nx = fmaf(h6, k1x + 2.0f * k2x + 2.0f * k3x + k4x, x1);
    ny = fmaf(h6, k1y + 2.0f * k2y + 2.0f * k3y + k4y, x2);
}

__global__ __launch_bounds__(256) void nct_rollout_kernel(
    const float* __restrict__ s0,      // (B, 2)
    const float* __restrict__ bparam,  // (B, 1)
    const float* __restrict__ W,       // (2, 1)
    const float* __restrict__ bias,    // (1,)
    const int* __restrict__ nsteps_p,  // (1,)
    float* __restrict__ out,           // (B, 1)
    int B) {
    int i = blockIdx.x * blockDim.x + threadIdx.x;
    if (i >= B) return;

    const float w0 = W[0];
    const float w1 = W[1];
    const float bs = bias[0];
    const int nsteps = nsteps_p[0];

    float2 s = reinterpret_cast<const float2*>(s0)[i];
    float x1 = s.x;
    float x2 = s.y;
    const float b = bparam[i];
    const float sinb = sinf(b);

    // c = b*u + sin_b, u = w0*x1 + w1*x2 + bias
    //   => c = alpha*x1 + beta*x2 + gamma
    const float alpha = b * w0;
    const float beta  = b * w1;
    const float gamma = fmaf(b, bs, sinb);

    // Build per-element affine step map: ns = A*s + d (constant across steps).
    float a00, a10, a01, a11, d0, d1;
    rk4_step(1.0f, 0.0f, alpha, a00, a10);
    rk4_step(0.0f, 1.0f, beta,  a01, a11);
    rk4_step(0.0f, 0.0f, gamma, d0,  d1);

    float accX = 0.0f;  // sum of x1(t+1)^2
    float accY = 0.0f;  // sum of x2(t+1)^2
    float accU = 0.0f;  // sum of u(t)^2
    #pragma unroll 4
    for (int t = 0; t < nsteps; ++t) {
        float u  = fmaf(w0, x1, fmaf(w1, x2, bs));
        float nx = fmaf(a00, x1, fmaf(a01, x2, d0));
        float ny = fmaf(a10, x1, fmaf(a11, x2, d1));
        accX = fmaf(nx, nx, accX);
        accY = fmaf(ny, ny, accY);
        accU = fmaf(u, u, accU);
        x1 = nx;
        x2 = ny;
    }

    float total = -DT_F * (P1_F * accX + P2_F * accY + PA_F * accU)
                  - TERM_SCALE_F * (fmaf(P1_F * x1, x1, P2_F * x2 * x2));
    out[i] = total;
}

extern "C" void kernel_launch(void* const* d_in, const int* in_sizes, int n_in,
                              void* d_out, int out_size, void* d_ws, size_t ws_size,
                              hipStream_t stream) {
    const float* s0     = (const float*)d_in[0];
    const float* bparam = (const float*)d_in[1];
    const float* W      = (const float*)d_in[2];
    const float* bias   = (const float*)d_in[3];
    const int*   nsteps = (const int*)d_in[4];
    float* out = (float*)d_out;
    const int B = in_sizes[1];  // b_param has B elements

    dim3 block(256);
    dim3 grid((B + 255) / 256);
    nct_rollout_kernel<<<grid, block, 0, stream>>>(s0, bparam, W, bias, nsteps,
                                                   out, B);
}

// Round 3
// 63.070 us; speedup vs baseline: 1.0997x; 1.0997x over previous
//
#include <hip/hip_runtime.h>

// NCT system simulator, round 3: closed-form log-time evaluation.
// The RK4 step with frozen u is affine in the homogeneous state h=(x1,x2,1):
//   h_{t+1} = T h_t,   T = [A d; 0 0 1]  (per-element constants).
// Per-step cost (positive sign) is h_tᵀ C h_t with
//   C = DT*(Tᵀ Q1 T + PA w̃ w̃ᵀ),  Q1 = diag(P1,P2,0),  w̃ = (w0,w1,bias).
// Total = -h0ᵀ ( S_n + TERM_SCALE * Tⁿᵀ Q1 Tⁿ ) h0,  S_n = Σ_{t<n} Tᵗᵀ C Tᵗ.
// Computed by square-and-multiply:  S_{a+b} = S_a + T_aᵀ S_b T_a, T_{a+b}=T_b T_a.
// 512 steps -> 9 doublings + 1 combine ≈ 500 FMA/thread (vs 4608 for the loop).

#define DT_F 0.01f
#define P1_F 1.0f
#define P2_F 0.1f
#define PA_F 0.01f
#define TERM_SCALE_F 10.0f

// One RK4 step of ds/dt = (x2, x1 + c) with c constant over the step.
__device__ __forceinline__ void rk4_step(float x1, float x2, float c,
                                         float& nx, float& ny) {
    const float h  = DT_F;
    const float hh = 0.5f * DT_F;
    const float h6 = DT_F / 6.0f;
    float k1x = x2;
    float k1y = x1 + c;
    float a2x = fmaf(hh, k1x, x1);
    float a2y = fmaf(hh, k1y, x2);
    float k2x = a2y;
    float k2y = a2x + c;
    float a3x = fmaf(hh, k2x, x1);
    float a3y = fmaf(hh, k2y, x2);
    float k3x = a3y;
    float k3y = a3x + c;
    float a4x = fmaf(h, k3x, x1);
    float a4y = fmaf(h, k3y, x2);
    float k4x = a4y;
    float k4y = a4x + c;
    nx = fmaf(h6, k1x + 2.0f * k2x + 2.0f * k3x + k4x, x1);
    ny = fmaf(h6, k1y + 2.0f * k2y + 2.0f * k3y + k4y, x2);
}

// R = Tᵀ S T for symmetric S (6 unique entries) and affine T=[A d; 0 0 1].
__device__ __forceinline__ void congr(
    float s00, float s01, float s02, float s11, float s12, float s22,
    float a00, float a01, float a10, float a11, float d0, float d1,
    float& r00, float& r01, float& r02, float& r11, float& r12, float& r22) {
    // M = S * T  (only rows 0,1 and col 2 of row 2 needed)
    float M00 = fmaf(s00, a00, s01 * a10);
    float M01 = fmaf(s00, a01, s01 * a11);
    float M02 = fmaf(s00, d0, fmaf(s01, d1, s02));
    float M10 = fmaf(s01, a00, s11 * a10);
    float M11 = fmaf(s01, a01, s11 * a11);
    float M12 = fmaf(s01, d0, fmaf(s11, d1, s12));
    float M22 = fmaf(s02, d0, fmaf(s12, d1, s22));
    // R = Tᵀ M (symmetric)
    r00 = fmaf(a00, M00, a10 * M10);
    r01 = fmaf(a00, M01, a10 * M11);
    r02 = fmaf(a00, M02, a10 * M12);
    r11 = fmaf(a01, M01, a11 * M11);
    r12 = fmaf(a01, M02, a11 * M12);
    r22 = fmaf(d0, M02, fmaf(d1, M12, M22));
}

// C = Tb ∘ Ta (apply Ta first, then Tb): A = Ab*Aa, d = Ab*da + db.
__device__ __forceinline__ void compose(
    float b00, float b01, float b10, float b11, float bd0, float bd1,
    float a00, float a01, float a10, float a11, float ad0, float ad1,
    float& c00, float& c01, float& c10, float& c11, float& cd0, float& cd1) {
    c00 = fmaf(b00, a00, b01 * a10);
    c01 = fmaf(b00, a01, b01 * a11);
    c10 = fmaf(b10, a00, b11 * a10);
    c11 = fmaf(b10, a01, b11 * a11);
    cd0 = fmaf(b00, ad0, fmaf(b01, ad1, bd0));
    cd1 = fmaf(b10, ad0, fmaf(b11, ad1, bd1));
}

__global__ __launch_bounds__(256) void nct_doubling_kernel(
    const float* __restrict__ s0,      // (B, 2)
    const float* __restrict__ bparam,  // (B, 1)
    const float* __restrict__ W,       // (2, 1)
    const float* __restrict__ bias,    // (1,)
    const int* __restrict__ nsteps_p,  // (1,)
    float* __restrict__ out,           // (B, 1)
    int B) {
    int i = blockIdx.x * blockDim.x + threadIdx.x;
    if (i >= B) return;

    const float w0 = W[0];
    const float w1 = W[1];
    const float bs = bias[0];
    unsigned n = (unsigned)nsteps_p[0];

    float2 s = reinterpret_cast<const float2*>(s0)[i];
    const float x1 = s.x;
    const float x2 = s.y;
    const float bp = bparam[i];
    const float sinb = sinf(bp);

    // c = b*u + sin_b = alpha*x1 + beta*x2 + gamma
    const float alpha = bp * w0;
    const float beta  = bp * w1;
    const float gamma = fmaf(bp, bs, sinb);

    // One-step affine map T = [A d; 0 0 1] from basis evaluations.
    float t00, t10, t01, t11, td0, td1;
    rk4_step(1.0f, 0.0f, alpha, t00, t10);
    rk4_step(0.0f, 1.0f, beta,  t01, t11);
    rk4_step(0.0f, 0.0f, gamma, td0, td1);

    // C = DT*(Tᵀ Q1 T + PA w̃ w̃ᵀ); rows of T: r0=(t00,t01,td0), r1=(t10,t11,td1).
    float Sb00 = DT_F * fmaf(P1_F * t00, t00, fmaf(P2_F * t10, t10, PA_F * w0 * w0));
    float Sb01 = DT_F * fmaf(P1_F * t00, t01, fmaf(P2_F * t10, t11, PA_F * w0 * w1));
    float Sb02 = DT_F * fmaf(P1_F * t00, td0, fmaf(P2_F * t10, td1, PA_F * w0 * bs));
    float Sb11 = DT_F * fmaf(P1_F * t01, t01, fmaf(P2_F * t11, t11, PA_F * w1 * w1));
    float Sb12 = DT_F * fmaf(P1_F * t01, td0, fmaf(P2_F * t11, td1, PA_F * w1 * bs));
    float Sb22 = DT_F * fmaf(P1_F * td0, td0, fmaf(P2_F * td1, td1, PA_F * bs * bs));
    float b00 = t00, b01 = t01, b10 = t10, b11 = t11, bd0 = td0, bd1 = td1;

    // Result accumulator: S_res = 0, T_res = I.
    float Sr00 = 0.f, Sr01 = 0.f, Sr02 = 0.f, Sr11 = 0.f, Sr12 = 0.f, Sr22 = 0.f;
    float r00 = 1.f, r01 = 0.f, r10 = 0.f, r11 = 1.f, rd0 = 0.f, rd1 = 0.f;

    // Square-and-multiply over the bits of n (wave-uniform branches).
    while (n) {
        if (n & 1u) {
            float q00, q01, q02, q11, q12, q22;
            congr(Sb00, Sb01, Sb02, Sb11, Sb12, Sb22,
                  r00, r01, r10, r11, rd0, rd1,
                  q00, q01, q02, q11, q12, q22);
            Sr00 += q00; Sr01 += q01; Sr02 += q02;
            Sr11 += q11; Sr12 += q12; Sr22 += q22;
            float n00, n01, n10, n11, nd0, nd1;
            compose(b00, b01, b10, b11, bd0, bd1,
                    r00, r01, r10, r11, rd0, rd1,
                    n00, n01, n10, n11, nd0, nd1);
            r00 = n00; r01 = n01; r10 = n10; r11 = n11; rd0 = nd0; rd1 = nd1;
        }
        n >>= 1u;
        if (n) {
            float q00, q01, q02, q11, q12, q22;
            congr(Sb00, Sb01, Sb02, Sb11, Sb12, Sb22,
                  b00, b01, b10, b11, bd0, bd1,
                  q00, q01, q02, q11, q12, q22);
            Sb00 += q00; Sb01 += q01; Sb02 += q02;
            Sb11 += q11; Sb12 += q12; Sb22 += q22;
            float n00, n01, n10, n11, nd0, nd1;
            compose(b00, b01, b10, b11, bd0, bd1,
                    b00, b01, b10, b11, bd0, bd1,
                    n00, n01, n10, n11, nd0, nd1);
            b00 = n00; b01 = n01; b10 = n10; b11 = n11; bd0 = nd0; bd1 = nd1;
        }
    }

    // G = S_res + TERM_SCALE * T_resᵀ Q1 T_res; rows of T_res: (r00,r01,rd0),(r10,r11,rd1).
    float G00 = fmaf(TERM_SCALE_F, fmaf(P1_F * r00, r00, P2_F * r10 * r10), Sr00);
    float G01 = fmaf(TERM_SCALE_F, fmaf(P1_F * r00, r01, P2_F * r10 * r11), Sr01);
    float G02 = fmaf(TERM_SCALE_F, fmaf(P1_F * r00, rd0, P2_F * r10 * rd1), Sr02);
    float G11 = fmaf(TERM_SCALE_F, fmaf(P1_F * r01, r01, P2_F * r11 * r11), Sr11);
    float G12 = fmaf(TERM_SCALE_F, fmaf(P1_F * r01, rd0, P2_F * r11 * rd1), Sr12);
    float G22 = fmaf(TERM_SCALE_F, fmaf(P1_F * rd0, rd0, P2_F * rd1 * rd1), Sr22);

    // total = -h0ᵀ G h0, h0 = (x1, x2, 1)
    float q = fmaf(G00 * x1, x1,
              fmaf(2.0f * x1, fmaf(G01, x2, G02),
              fmaf(G11 * x2, x2,
              fmaf(2.0f * G12, x2, G22))));
    out[i] = -q;
}

extern "C" void kernel_launch(void* const* d_in, const int* in_sizes, int n_in,
                              void* d_out, int out_size, void* d_ws, size_t ws_size,
                              hipStream_t stream) {
    const float* s0     = (const float*)d_in[0];
    const float* bparam = (const float*)d_in[1];
    const float* W      = (const float*)d_in[2];
    const float* bias   = (const float*)d_in[3];
    const int*   nsteps = (const int*)d_in[4];
    float* out = (float*)d_out;
    const int B = in_sizes[1];  // b_param has B elements

    dim3 block(256);
    dim3 grid((B + 255) / 256);
    nct_doubling_kernel<<<grid, block, 0, stream>>>(s0, bparam, W, bias, nsteps,
                                                    out, B);
}